// Round 4
// baseline (160.768 us; speedup 1.0000x reference)
//
#include <hip/hip_runtime.h>
#include <math.h>

#define N 4096
#define NFEAT 1024
#define NHID 8
#define NHEADS 8
#define NCLS 16
#define CAP 128   // max neighbors/row; Binomial(4096,0.01) mean 41, 128 is >13 sigma

#define GEMM_BLOCKS 512   // blocks 0..511 = GEMM, 512..4607 = adj scan

// ============ Kernel A: block-specialized {GEMM+fsrc/fdst} | {CSR scan} ============
// GEMM path (512 blocks): 8 rows x 64 cols/block; x read DIRECTLY from global
// via wave-uniform float4 loads (single 16B segment broadcast, L1/L2-served) --
// no LDS staging, no staging barrier; LDS only for the 8KB cross-wave K-reduce.
// Scan path (4096 blocks): one row of adj (16KB) per block, 4 float4/thread
// issued up-front; nonzero columns appended to nbr via LDS atomic.
__global__ __launch_bounds__(256) void ka_scan_gemm(const float* __restrict__ adj,
                                                    const float* __restrict__ x,
                                                    const float* __restrict__ W_heads,
                                                    const float* __restrict__ a_heads,
                                                    int* __restrict__ deg,
                                                    int* __restrict__ nbr,
                                                    float* __restrict__ Wh,
                                                    float* __restrict__ fsrc,
                                                    float* __restrict__ fdst) {
    __shared__ float smem[4 * 8 * 64];   // 8 KB: GEMM K-reduction; scan uses [0] as cnt
    const int tid = threadIdx.x;

    if (blockIdx.x >= GEMM_BLOCKS) {
        // ---------------- scan path ----------------
        const int row = blockIdx.x - GEMM_BLOCKS;
        int* cnt = (int*)smem;
        if (tid == 0) *cnt = 0;
        __syncthreads();
        const float4* arow = (const float4*)(adj + (size_t)row * N);
        int* outl = nbr + (size_t)row * CAP;
        float4 v[4];
        #pragma unroll
        for (int i = 0; i < 4; ++i) v[i] = arow[tid + i * 256];   // 64B in flight/thread
        #pragma unroll
        for (int i = 0; i < 4; ++i) {
            const int b = (tid + i * 256) * 4;
            if (v[i].x > 0.f) { int p = atomicAdd(cnt, 1); if (p < CAP) outl[p] = b + 0; }
            if (v[i].y > 0.f) { int p = atomicAdd(cnt, 1); if (p < CAP) outl[p] = b + 1; }
            if (v[i].z > 0.f) { int p = atomicAdd(cnt, 1); if (p < CAP) outl[p] = b + 2; }
            if (v[i].w > 0.f) { int p = atomicAdd(cnt, 1); if (p < CAP) outl[p] = b + 3; }
        }
        __syncthreads();
        if (tid == 0) deg[row] = *cnt > CAP ? CAP : *cnt;
        return;
    }

    // ---------------- GEMM path ----------------
    float (*red)[8][64] = (float (*)[8][64])smem;  // [4][8][64]
    const int w = tid >> 6, c = tid & 63;
    const int row0 = blockIdx.x * 8;

    float acc[8] = {};
    // W_heads[h][f][kh]: element for k-index kk at wp[kk*8]
    const float* wp = W_heads + (size_t)(c >> 3) * (NFEAT * NHID) + (c & 7)
                    + (size_t)(w * 256) * NHID;
    // x base for this wave's K-slice: wave-uniform addresses -> broadcast loads
    const float* xb = x + (size_t)row0 * NFEAT + w * 256;
    for (int k = 0; k < 256; k += 8) {
        float wv[8];
        #pragma unroll
        for (int u = 0; u < 8; ++u) wv[u] = wp[(k + u) * 8];    // 8 indep loads, L2-hot
        #pragma unroll
        for (int r = 0; r < 8; ++r) {
            const float4 a0 = *(const float4*)(xb + r * NFEAT + k);     // uniform, 16B seg
            const float4 a1 = *(const float4*)(xb + r * NFEAT + k + 4);
            acc[r] += a0.x * wv[0] + a0.y * wv[1] + a0.z * wv[2] + a0.w * wv[3]
                    + a1.x * wv[4] + a1.y * wv[5] + a1.z * wv[6] + a1.w * wv[7];
        }
    }
    #pragma unroll
    for (int r = 0; r < 8; ++r) red[w][r][c] = acc[r];
    __syncthreads();
    #pragma unroll
    for (int e0 = 0; e0 < 2; ++e0) {
        int e = tid + e0 * 256;
        int r = e >> 6, cc = e & 63;
        float v = red[0][r][cc] + red[1][r][cc] + red[2][r][cc] + red[3][r][cc];
        Wh[(size_t)(row0 + r) * 64 + cc] = v;
        int h = cc >> 3, kh = cc & 7;
        float vs = v * a_heads[h * 16 + kh];
        float vd = v * a_heads[h * 16 + 8 + kh];
        vs += __shfl_xor(vs, 1); vs += __shfl_xor(vs, 2); vs += __shfl_xor(vs, 4);
        vd += __shfl_xor(vd, 1); vd += __shfl_xor(vd, 2); vd += __shfl_xor(vd, 4);
        if (kh == 0) { fsrc[h * N + row0 + r] = vs; fdst[h * N + row0 + r] = vd; }
    }
}

// ======= Kernel B: layer-1 softmax + aggregate + ELU + projection (ILP layout) =====
// One wave per row. lane = (h = lane>>3, nn = lane&7). Round r assigns lane its
// OWN neighbor n = r*8+nn: nl load = one 32B broadcast segment, fd gather
// 64-wide, Wh read = lane's own 32B feature slice. All rounds' loads
// independent. Lane accumulates 8 feature-partials; 7-shuffle transpose-reduce
// over the 8-lane head group yields feature f = lane for the W_final epilogue.
__global__ __launch_bounds__(256) void kb_attn1(const float* __restrict__ fsrc,
                                                const float* __restrict__ fdst,
                                                const float* __restrict__ Wh,
                                                const int* __restrict__ deg,
                                                const int* __restrict__ nbr,
                                                const float* __restrict__ W_final,
                                                const float* __restrict__ a_final,
                                                float* __restrict__ Wh2,
                                                float* __restrict__ fsrc2,
                                                float* __restrict__ fdst2) {
    __shared__ float hrow[4][64];
    const int wave = threadIdx.x >> 6;
    const int lane = threadIdx.x & 63;
    const int row = blockIdx.x * 4 + wave;
    const int h = lane >> 3;
    const int nn = lane & 7;
    const int d = deg[row];
    const int* nl = nbr + (size_t)row * CAP;
    const float fs = fsrc[h * N + row];
    const float* fd = fdst + h * N;

    float pacc[8] = {0.f, 0.f, 0.f, 0.f, 0.f, 0.f, 0.f, 0.f};
    float sp = 0.f;   // partial softmax denom for head h (this lane's neighbor subset)

    #pragma unroll
    for (int r = 0; r < 16; ++r) {
        if (r * 8 < d) {
            const int n = r * 8 + nn;
            const bool vv = n < d;
            const int j = vv ? nl[n] : 0;
            const float e = fs + fd[j];
            const float w = vv ? __expf(fmaxf(e, 0.2f * e)) : 0.f;
            sp += w;
            const float4 wv0 = *(const float4*)(Wh + (size_t)j * 64 + h * 8);
            const float4 wv1 = *(const float4*)(Wh + (size_t)j * 64 + h * 8 + 4);
            pacc[0] += w * wv0.x; pacc[1] += w * wv0.y;
            pacc[2] += w * wv0.z; pacc[3] += w * wv0.w;
            pacc[4] += w * wv1.x; pacc[5] += w * wv1.y;
            pacc[6] += w * wv1.z; pacc[7] += w * wv1.w;
        }
    }

    // softmax denom: all-reduce over the 8-lane head group
    sp += __shfl_xor(sp, 1);
    sp += __shfl_xor(sp, 2);
    sp += __shfl_xor(sp, 4);

    // transpose-reduce (reduce-scatter): lane (h,nn) ends with full sum of
    // feature h*8+nn. All selects use constant indices (no scratch spill).
    const int k0 = nn & 1, k1 = (nn >> 1) & 1, k2 = nn >> 2;
    float t0 = (k0 ? pacc[1] : pacc[0]) + __shfl_xor(k0 ? pacc[0] : pacc[1], 1);
    float t1 = (k0 ? pacc[3] : pacc[2]) + __shfl_xor(k0 ? pacc[2] : pacc[3], 1);
    float t2 = (k0 ? pacc[5] : pacc[4]) + __shfl_xor(k0 ? pacc[4] : pacc[5], 1);
    float t3 = (k0 ? pacc[7] : pacc[6]) + __shfl_xor(k0 ? pacc[6] : pacc[7], 1);
    float u0 = (k1 ? t1 : t0) + __shfl_xor(k1 ? t0 : t1, 2);
    float u1 = (k1 ? t3 : t2) + __shfl_xor(k1 ? t2 : t3, 2);
    float of = (k2 ? u1 : u0) + __shfl_xor(k2 ? u0 : u1, 4);

    float o = of / sp;
    o = o > 0.f ? o : (__expf(o) - 1.f);   // ELU
    hrow[wave][lane] = o;
    __syncthreads();

    // epilogue: Wh2 = elu(h1) @ W_final, fsrc2/fdst2 via shuffles
    const int g = lane >> 4, cc = lane & 15;
    float p = 0.f;
    #pragma unroll
    for (int f0 = 0; f0 < 16; ++f0) {
        int f = g * 16 + f0;
        p += hrow[wave][f] * W_final[f * 16 + cc];
    }
    p += __shfl_xor(p, 16);
    p += __shfl_xor(p, 32);                // all lanes hold Wh2[row][cc]
    if (g == 0) Wh2[(size_t)row * 16 + cc] = p;
    float vs = p * a_final[cc];
    float vd = p * a_final[16 + cc];
    #pragma unroll
    for (int mm = 1; mm < 16; mm <<= 1) {
        vs += __shfl_xor(vs, mm);
        vd += __shfl_xor(vd, mm);
    }
    if (lane == 0) { fsrc2[row] = vs; fdst2[row] = vd; }
}

// ======= Kernel C: layer-2 softmax + aggregate + log_softmax (ILP layout) ==========
// One wave per row. Weights for neighbors 0..63 computed lane-parallel in ONE
// shot (lane n -> w[n]); denom via 6 shfl_xor. Aggregation (lane = jj slice,
// c class) pulls j,w from registers via __shfl -- no memory op in the chain
// except the L2-hot Wh2 row read. 2-way unrolled for load ILP.
__global__ __launch_bounds__(256) void kc_attn2(const float* __restrict__ fsrc2,
                                                const float* __restrict__ fdst2,
                                                const float* __restrict__ Wh2,
                                                const int* __restrict__ deg,
                                                const int* __restrict__ nbr,
                                                float* __restrict__ out) {
    const int wave = threadIdx.x >> 6;
    const int lane = threadIdx.x & 63;
    const int row = blockIdx.x * 4 + wave;
    const int jj = lane >> 4, c = lane & 15;
    const int d = deg[row];
    const int* nl = nbr + (size_t)row * CAP;
    const float fs = fsrc2[row];

    // lane-parallel weight computation (chunk 0: neighbors 0..63)
    const bool v0 = lane < d;
    const int jl0 = v0 ? nl[lane] : 0;
    const float e0 = fs + fdst2[jl0];
    const float w0 = v0 ? __expf(fmaxf(e0, 0.2f * e0)) : 0.f;

    int jl1 = 0;
    float w1 = 0.f;
    if (__builtin_expect(d > 64, 0)) {     // rare (~1 row in 4096)
        const bool v1 = 64 + lane < d;
        const int jx = v1 ? nl[64 + lane] : 0;
        jl1 = jx;
        const float e1 = fs + fdst2[jx];
        w1 = v1 ? __expf(fmaxf(e1, 0.2f * e1)) : 0.f;
    }

    float s = w0 + w1;
    #pragma unroll
    for (int mm = 1; mm < 64; mm <<= 1) s += __shfl_xor(s, mm);

    // aggregation: slice jj handles n = jj, jj+4, ...; j/w broadcast from regs
    const int dc = d < 64 ? d : 64;
    float acc = 0.f, acc2 = 0.f;
    int n = jj;
    for (; n + 4 < dc; n += 8) {
        const int ja = __shfl(jl0, n);
        const float wa = __shfl(w0, n);
        const int jb = __shfl(jl0, n + 4);
        const float wb = __shfl(w0, n + 4);
        acc  += wa * Wh2[(size_t)ja * 16 + c];
        acc2 += wb * Wh2[(size_t)jb * 16 + c];
    }
    if (n < dc) {
        const int ja = __shfl(jl0, n);
        const float wa = __shfl(w0, n);
        acc += wa * Wh2[(size_t)ja * 16 + c];
    }
    if (__builtin_expect(d > 64, 0)) {
        for (int m = 64 + jj; m < d; m += 4) {
            const int jb = __shfl(jl1, m - 64);
            const float wb = __shfl(w1, m - 64);
            acc2 += wb * Wh2[(size_t)jb * 16 + c];
        }
    }
    acc += acc2;
    acc += __shfl_xor(acc, 16);
    acc += __shfl_xor(acc, 32);

    float u = acc / s;
    float m2 = u;
    #pragma unroll
    for (int mm = 1; mm < 16; mm <<= 1) m2 = fmaxf(m2, __shfl_xor(m2, mm));
    float tv = u - m2;
    float se = __expf(tv);
    #pragma unroll
    for (int mm = 1; mm < 16; mm <<= 1) se += __shfl_xor(se, mm);
    float o = tv - logf(se);
    if (jj == 0) out[(size_t)row * 16 + c] = o;
}

extern "C" void kernel_launch(void* const* d_in, const int* in_sizes, int n_in,
                              void* d_out, int out_size, void* d_ws, size_t ws_size,
                              hipStream_t stream) {
    const float* x       = (const float*)d_in[0];
    const float* adj     = (const float*)d_in[1];
    const float* W_heads = (const float*)d_in[2];
    const float* a_heads = (const float*)d_in[3];
    const float* W_final = (const float*)d_in[4];
    const float* a_final = (const float*)d_in[5];
    float* out = (float*)d_out;

    float* ws    = (float*)d_ws;
    float* Wh    = ws;                 // 4096*64 = 262144
    float* fsrc  = Wh + 262144;        // 32768
    float* fdst  = fsrc + 32768;       // 32768
    float* Wh2   = fdst + 32768;       // 65536
    float* fsrc2 = Wh2 + 65536;        // 4096
    float* fdst2 = fsrc2 + 4096;       // 4096
    int*   deg   = (int*)(fdst2 + 4096);       // 4096 ints
    int*   nbr   = deg + 4096;                 // 4096*128 ints (~3.7 MB total)

    ka_scan_gemm<<<GEMM_BLOCKS + N, 256, 0, stream>>>(adj, x, W_heads, a_heads,
                                                      deg, nbr, Wh, fsrc, fdst);
    kb_attn1    <<<N / 4, 256, 0, stream>>>(fsrc, fdst, Wh, deg, nbr,
                                            W_final, a_final, Wh2, fsrc2, fdst2);
    kc_attn2    <<<N / 4, 256, 0, stream>>>(fsrc2, fdst2, Wh2, deg, nbr, out);
}

// Round 5
// 135.240 us; speedup vs baseline: 1.1888x; 1.1888x over previous
//
#include <hip/hip_runtime.h>
#include <math.h>

#define N 4096
#define NFEAT 1024
#define NHID 8
#define NHEADS 8
#define NCLS 16
#define CAP 128   // max neighbors/row; Binomial(4096,0.01) mean 41, 128 is >13 sigma

#define GEMM_BLOCKS 512   // blocks 0..511 = GEMM, 512..4607 = adj scan

// ============ Kernel A: block-specialized {GEMM+fsrc/fdst} | {CSR scan} ============
// ROUND-1 PROVEN VERSION (reverted): x staged in LDS (coalesced, pays global
// latency once); direct-global variant was a latency-bound regression (r4).
__global__ __launch_bounds__(256) void ka_scan_gemm(const float* __restrict__ adj,
                                                    const float* __restrict__ x,
                                                    const float* __restrict__ W_heads,
                                                    const float* __restrict__ a_heads,
                                                    int* __restrict__ deg,
                                                    int* __restrict__ nbr,
                                                    float* __restrict__ Wh,
                                                    float* __restrict__ fsrc,
                                                    float* __restrict__ fdst) {
    __shared__ float smem[8 * NFEAT + 4 * 8 * 64];   // 40 KB (gemm); scan uses [0] as cnt
    const int tid = threadIdx.x;

    if (blockIdx.x >= GEMM_BLOCKS) {
        // ---------------- scan path ----------------
        const int row = blockIdx.x - GEMM_BLOCKS;
        int* cnt = (int*)smem;
        if (tid == 0) *cnt = 0;
        __syncthreads();
        const float4* arow = (const float4*)(adj + (size_t)row * N);
        int* outl = nbr + (size_t)row * CAP;
        float4 v[4];
        #pragma unroll
        for (int i = 0; i < 4; ++i) v[i] = arow[tid + i * 256];   // 64B in flight/thread
        #pragma unroll
        for (int i = 0; i < 4; ++i) {
            const int b = (tid + i * 256) * 4;
            if (v[i].x > 0.f) { int p = atomicAdd(cnt, 1); if (p < CAP) outl[p] = b + 0; }
            if (v[i].y > 0.f) { int p = atomicAdd(cnt, 1); if (p < CAP) outl[p] = b + 1; }
            if (v[i].z > 0.f) { int p = atomicAdd(cnt, 1); if (p < CAP) outl[p] = b + 2; }
            if (v[i].w > 0.f) { int p = atomicAdd(cnt, 1); if (p < CAP) outl[p] = b + 3; }
        }
        __syncthreads();
        if (tid == 0) deg[row] = *cnt > CAP ? CAP : *cnt;
        return;
    }

    // ---------------- GEMM path ----------------
    float* xs = smem;                       // 8*1024 floats
    float (*red)[8][64] = (float (*)[8][64])(smem + 8 * NFEAT);  // [4][8][64]
    const int w = tid >> 6, c = tid & 63;
    const int row0 = blockIdx.x * 8;

    const float4* xg = (const float4*)(x + (size_t)row0 * NFEAT);
    float4* xls = (float4*)xs;
    #pragma unroll
    for (int i = 0; i < 8; ++i) xls[tid + i * 256] = xg[tid + i * 256];
    __syncthreads();

    float acc[8] = {};
    // W_heads[h][f][kh]: element for k-index kk at wp[kk*8]
    const float* wp = W_heads + (size_t)(c >> 3) * (NFEAT * NHID) + (c & 7)
                    + (size_t)(w * 256) * NHID;
    const float* xw = xs + w * 256;
    for (int k = 0; k < 256; k += 8) {
        float wv[8];
        #pragma unroll
        for (int u = 0; u < 8; ++u) wv[u] = wp[(k + u) * 8];    // 8 indep loads, L2-hot
        #pragma unroll
        for (int r = 0; r < 8; ++r) {
            const float4 a0 = *(const float4*)(xw + r * NFEAT + k);     // broadcast LDS
            const float4 a1 = *(const float4*)(xw + r * NFEAT + k + 4);
            acc[r] += a0.x * wv[0] + a0.y * wv[1] + a0.z * wv[2] + a0.w * wv[3]
                    + a1.x * wv[4] + a1.y * wv[5] + a1.z * wv[6] + a1.w * wv[7];
        }
    }
    #pragma unroll
    for (int r = 0; r < 8; ++r) red[w][r][c] = acc[r];
    __syncthreads();
    #pragma unroll
    for (int e0 = 0; e0 < 2; ++e0) {
        int e = tid + e0 * 256;
        int r = e >> 6, cc = e & 63;
        float v = red[0][r][cc] + red[1][r][cc] + red[2][r][cc] + red[3][r][cc];
        Wh[(size_t)(row0 + r) * 64 + cc] = v;
        int h = cc >> 3, kh = cc & 7;
        float vs = v * a_heads[h * 16 + kh];
        float vd = v * a_heads[h * 16 + 8 + kh];
        vs += __shfl_xor(vs, 1); vs += __shfl_xor(vs, 2); vs += __shfl_xor(vs, 4);
        vd += __shfl_xor(vd, 1); vd += __shfl_xor(vd, 2); vd += __shfl_xor(vd, 4);
        if (kh == 0) { fsrc[h * N + row0 + r] = vs; fdst[h * N + row0 + r] = vd; }
    }
}

// ======= Kernel B: layer-1 attention — 2 WAVES PER ROW (occupancy 16->32 w/CU) =====
// Block = 2 rows x 2 waves. Wave half hh covers neighbor rounds base = r*16+hh*8;
// lane = (h = lane>>3, nn = lane&7) as before. Partials (pacc[8], sp) combined
// across the wave pair via LDS; wave hh=0 then does the unchanged transpose-
// reduce + ELU + W_final projection epilogue.
__global__ __launch_bounds__(256) void kb_attn1(const float* __restrict__ fsrc,
                                                const float* __restrict__ fdst,
                                                const float* __restrict__ Wh,
                                                const int* __restrict__ deg,
                                                const int* __restrict__ nbr,
                                                const float* __restrict__ W_final,
                                                const float* __restrict__ a_final,
                                                float* __restrict__ Wh2,
                                                float* __restrict__ fsrc2,
                                                float* __restrict__ fdst2) {
    __shared__ float comb[2][64][9];   // [row][lane][pacc0..7, sp]
    __shared__ float hrow[2][64];
    const int wave = threadIdx.x >> 6;
    const int lane = threadIdx.x & 63;
    const int rw = wave >> 1;          // row within block
    const int hh = wave & 1;           // neighbor-half index
    const int row = blockIdx.x * 2 + rw;
    const int h = lane >> 3;
    const int nn = lane & 7;
    const int d = deg[row];
    const int* nl = nbr + (size_t)row * CAP;
    const float fs = fsrc[h * N + row];
    const float* fd = fdst + h * N;

    float pacc[8] = {0.f, 0.f, 0.f, 0.f, 0.f, 0.f, 0.f, 0.f};
    float sp = 0.f;

    #pragma unroll
    for (int r = 0; r < 8; ++r) {
        const int base = r * 16 + hh * 8;   // wave-uniform
        if (base < d) {
            const int n = base + nn;
            const bool vv = n < d;
            const int j = vv ? nl[n] : 0;
            const float e = fs + fd[j];
            const float w = vv ? __expf(fmaxf(e, 0.2f * e)) : 0.f;
            sp += w;
            const float4 wv0 = *(const float4*)(Wh + (size_t)j * 64 + h * 8);
            const float4 wv1 = *(const float4*)(Wh + (size_t)j * 64 + h * 8 + 4);
            pacc[0] += w * wv0.x; pacc[1] += w * wv0.y;
            pacc[2] += w * wv0.z; pacc[3] += w * wv0.w;
            pacc[4] += w * wv1.x; pacc[5] += w * wv1.y;
            pacc[6] += w * wv1.z; pacc[7] += w * wv1.w;
        }
    }

    if (hh == 1) {
        #pragma unroll
        for (int i = 0; i < 8; ++i) comb[rw][lane][i] = pacc[i];
        comb[rw][lane][8] = sp;
    }
    __syncthreads();
    if (hh == 1) return;    // no barriers after this point

    #pragma unroll
    for (int i = 0; i < 8; ++i) pacc[i] += comb[rw][lane][i];
    sp += comb[rw][lane][8];

    // softmax denom: all-reduce over the 8-lane head group
    sp += __shfl_xor(sp, 1);
    sp += __shfl_xor(sp, 2);
    sp += __shfl_xor(sp, 4);

    // transpose-reduce: lane (h,nn) ends with full sum of feature h*8+nn
    const int k0 = nn & 1, k1 = (nn >> 1) & 1, k2 = nn >> 2;
    float t0 = (k0 ? pacc[1] : pacc[0]) + __shfl_xor(k0 ? pacc[0] : pacc[1], 1);
    float t1 = (k0 ? pacc[3] : pacc[2]) + __shfl_xor(k0 ? pacc[2] : pacc[3], 1);
    float t2 = (k0 ? pacc[5] : pacc[4]) + __shfl_xor(k0 ? pacc[4] : pacc[5], 1);
    float t3 = (k0 ? pacc[7] : pacc[6]) + __shfl_xor(k0 ? pacc[6] : pacc[7], 1);
    float u0 = (k1 ? t1 : t0) + __shfl_xor(k1 ? t0 : t1, 2);
    float u1 = (k1 ? t3 : t2) + __shfl_xor(k1 ? t2 : t3, 2);
    float of = (k2 ? u1 : u0) + __shfl_xor(k2 ? u0 : u1, 4);

    float o = of / sp;
    o = o > 0.f ? o : (__expf(o) - 1.f);   // ELU
    hrow[rw][lane] = o;                    // same-wave LDS RAW: no barrier needed

    // projection epilogue: Wh2 = elu(h1) @ W_final ; fsrc2/fdst2 via shuffles
    const int g = lane >> 4, cc = lane & 15;
    float p = 0.f;
    #pragma unroll
    for (int f0 = 0; f0 < 16; ++f0) {
        int f = g * 16 + f0;
        p += hrow[rw][f] * W_final[f * 16 + cc];
    }
    p += __shfl_xor(p, 16);
    p += __shfl_xor(p, 32);                // all lanes hold Wh2[row][cc]
    if (g == 0) Wh2[(size_t)row * 16 + cc] = p;
    float vs = p * a_final[cc];
    float vd = p * a_final[16 + cc];
    #pragma unroll
    for (int mm = 1; mm < 16; mm <<= 1) {
        vs += __shfl_xor(vs, mm);
        vd += __shfl_xor(vd, mm);
    }
    if (lane == 0) { fsrc2[row] = vs; fdst2[row] = vd; }
}

// ======= Kernel C: layer-2 attention — 2 WAVES PER ROW ==========================
// Block = 2 rows x 2 waves. Wave hh owns interleaved neighbors n = 2*lane + hh
// (the pair covers exactly CAP=128 -> no d>64 special case). Per-wave partial
// {acc (per class), s} combined via LDS; wave hh=0 does log_softmax + store.
__global__ __launch_bounds__(256) void kc_attn2(const float* __restrict__ fsrc2,
                                                const float* __restrict__ fdst2,
                                                const float* __restrict__ Wh2,
                                                const int* __restrict__ deg,
                                                const int* __restrict__ nbr,
                                                float* __restrict__ out) {
    __shared__ float accv[2][16];
    __shared__ float sv[2];
    const int wave = threadIdx.x >> 6;
    const int lane = threadIdx.x & 63;
    const int rw = wave >> 1, hh = wave & 1;
    const int row = blockIdx.x * 2 + rw;
    const int jj = lane >> 4, c = lane & 15;
    const int d = deg[row];
    const int* nl = nbr + (size_t)row * CAP;
    const float fs = fsrc2[row];

    // lane-parallel weights: this wave's neighbor n = 2*lane + hh
    const int n0 = 2 * lane + hh;
    const bool v0 = n0 < d;
    const int jl0 = v0 ? nl[n0] : 0;
    const float e0 = fs + fdst2[jl0];
    const float w0 = v0 ? __expf(fmaxf(e0, 0.2f * e0)) : 0.f;

    float s = w0;
    #pragma unroll
    for (int mm = 1; mm < 64; mm <<= 1) s += __shfl_xor(s, mm);

    // local aggregation: local index l <-> neighbor 2l+hh; dl = #local neighbors
    const int dl = (d - hh + 1) >> 1;
    float acc = 0.f, acc2 = 0.f;
    int l = jj;
    for (; l + 4 < dl; l += 8) {
        const int ja = __shfl(jl0, l);
        const float wa = __shfl(w0, l);
        const int jb = __shfl(jl0, l + 4);
        const float wb = __shfl(w0, l + 4);
        acc  += wa * Wh2[(size_t)ja * 16 + c];
        acc2 += wb * Wh2[(size_t)jb * 16 + c];
    }
    if (l < dl) {
        const int ja = __shfl(jl0, l);
        const float wa = __shfl(w0, l);
        acc += wa * Wh2[(size_t)ja * 16 + c];
    }
    acc += acc2;
    acc += __shfl_xor(acc, 16);
    acc += __shfl_xor(acc, 32);   // all lanes: wave-partial for class c

    if (hh == 1) {
        if (lane < 16) accv[rw][lane] = acc;
        if (lane == 0) sv[rw] = s;
    }
    __syncthreads();
    if (hh == 1) return;          // no barriers after this point

    acc += accv[rw][c];
    s += sv[rw];

    float u = acc / s;
    float m2 = u;
    #pragma unroll
    for (int mm = 1; mm < 16; mm <<= 1) m2 = fmaxf(m2, __shfl_xor(m2, mm));
    float tv = u - m2;
    float se = __expf(tv);
    #pragma unroll
    for (int mm = 1; mm < 16; mm <<= 1) se += __shfl_xor(se, mm);
    float o = tv - logf(se);
    if (jj == 0) out[(size_t)row * 16 + c] = o;
}

extern "C" void kernel_launch(void* const* d_in, const int* in_sizes, int n_in,
                              void* d_out, int out_size, void* d_ws, size_t ws_size,
                              hipStream_t stream) {
    const float* x       = (const float*)d_in[0];
    const float* adj     = (const float*)d_in[1];
    const float* W_heads = (const float*)d_in[2];
    const float* a_heads = (const float*)d_in[3];
    const float* W_final = (const float*)d_in[4];
    const float* a_final = (const float*)d_in[5];
    float* out = (float*)d_out;

    float* ws    = (float*)d_ws;
    float* Wh    = ws;                 // 4096*64 = 262144
    float* fsrc  = Wh + 262144;        // 32768
    float* fdst  = fsrc + 32768;       // 32768
    float* Wh2   = fdst + 32768;       // 65536
    float* fsrc2 = Wh2 + 65536;        // 4096
    float* fdst2 = fsrc2 + 4096;       // 4096
    int*   deg   = (int*)(fdst2 + 4096);       // 4096 ints
    int*   nbr   = deg + 4096;                 // 4096*128 ints (~3.7 MB total)

    ka_scan_gemm<<<GEMM_BLOCKS + N, 256, 0, stream>>>(adj, x, W_heads, a_heads,
                                                      deg, nbr, Wh, fsrc, fdst);
    kb_attn1    <<<N / 2, 256, 0, stream>>>(fsrc, fdst, Wh, deg, nbr,
                                            W_final, a_final, Wh2, fsrc2, fdst2);
    kc_attn2    <<<N / 2, 256, 0, stream>>>(fsrc2, fdst2, Wh2, deg, nbr, out);
}